// Round 8
// baseline (10.322 us; speedup 1.0000x reference)
//
#include <hip/hip_runtime.h>

// MPSELoss one-dispatch, 8 blocks x 1024 threads (4 rows per block).
// loss = sum_b [ N*sum_i d_bi^2 - (sum_i d_bi)^2 ] / (B * N*(N-1)/2),  d = outputs - targets
//
// Cross-block combine, HARDENED after R7's race: every cross-block access is a real
// atomic RMW executing at the LLC (coherence point):
//   - slot write  = atomic_exchange (relaxed, agent)  -> global_atomic_swap, ack from LLC
//   - s_waitcnt vmcnt(0)                               -> slot value IS in LLC
//   - counter bump = fetch_add (relaxed, agent)        -> strictly later at LLC
//   - winner reads = fetch_add(slot, 0.0) RMWs         -> read the LLC value, no caches
// R7's failure mode (plain sc1 store ack'd from a write buffer, counter RMW overtaking
// it in the fabric) is impossible here: swaps and adds both execute at the LLC, and the
// winner never issues a plain/cacheable load. No acquire/release -> no buffer_wbl2/inv.
// Winner test (prev & 7) == 7 fires exactly once per call for ANY initial counter value
// (0xAA poison harmless). Fixed-order sums -> bit-deterministic.

#define BB 32
#define NN 2048
#define NBLK 8
#define RPB (BB / NBLK)   // 4 rows per block, 256 threads per row

__global__ void __launch_bounds__(1024) mpse_hard8(const float* __restrict__ outs,
                                                   const float* __restrict__ tgts,
                                                   double* __restrict__ slots,
                                                   unsigned int* __restrict__ counter,
                                                   float* __restrict__ out) {
    const int t = threadIdx.x;
    const int g = t >> 8;                 // row-group 0..3 within block
    const int idx = t & 255;              // thread within row-group
    const int row = blockIdx.x * RPB + g;

    const float4* o4 = reinterpret_cast<const float4*>(outs + (size_t)row * NN);
    const float4* g4 = reinterpret_cast<const float4*>(tgts + (size_t)row * NN);

    float s1 = 0.f, s2 = 0.f;
    // 512 float4 per row; 256 threads/row -> 2 float4 each per tensor, coalesced 4KB segs.
#pragma unroll
    for (int k = 0; k < 2; ++k) {
        float4 a = o4[idx + k * 256];
        float4 b = g4[idx + k * 256];
        float d0 = a.x - b.x;
        float d1 = a.y - b.y;
        float d2 = a.z - b.z;
        float d3 = a.w - b.w;
        s1 += (d0 + d1) + (d2 + d3);
        s2 += (d0 * d0 + d1 * d1) + (d2 * d2 + d3 * d3);
    }

    // wave64 butterfly
#pragma unroll
    for (int off = 32; off >= 1; off >>= 1) {
        s1 += __shfl_xor(s1, off);
        s2 += __shfl_xor(s2, off);
    }

    // 16 waves; row g owns waves 4g..4g+3
    __shared__ float sh1[16];
    __shared__ float sh2[16];
    const int wave = t >> 6;
    if ((t & 63) == 0) {
        sh1[wave] = s1;
        sh2[wave] = s2;
    }
    __syncthreads();

    if (t == 0) {
        double acc = 0.0;
#pragma unroll
        for (int r = 0; r < RPB; ++r) {   // fixed order over this block's 4 rows
            float S1 = (sh1[4 * r] + sh1[4 * r + 1]) + (sh1[4 * r + 2] + sh1[4 * r + 3]);
            float S2 = (sh2[4 * r] + sh2[4 * r + 1]) + (sh2[4 * r + 2] + sh2[4 * r + 3]);
            acc += (double)NN * (double)S2 - (double)S1 * (double)S1;
        }

        // real atomic swap: executes at LLC, vmcnt ack from LLC
        (void)__hip_atomic_exchange(&slots[blockIdx.x], acc, __ATOMIC_RELAXED,
                                    __HIP_MEMORY_SCOPE_AGENT);
        asm volatile("s_waitcnt vmcnt(0)" ::: "memory");  // slot value IS in LLC now

        unsigned int prev = __hip_atomic_fetch_add(counter, 1u, __ATOMIC_RELAXED,
                                                   __HIP_MEMORY_SCOPE_AGENT);
        if ((prev & (NBLK - 1)) == (NBLK - 1)) {
            // winner: read each slot via an RMW (fetch_add 0.0) -> LLC value, no caches
            double total = 0.0;
#pragma unroll
            for (int r = 0; r < NBLK; ++r) {
                total += __hip_atomic_fetch_add(&slots[r], 0.0, __ATOMIC_RELAXED,
                                                __HIP_MEMORY_SCOPE_AGENT);
            }
            const double count = (double)BB * ((double)NN * (double)(NN - 1) * 0.5);
            out[0] = (float)(total / count);
        }
    }
}

extern "C" void kernel_launch(void* const* d_in, const int* in_sizes, int n_in,
                              void* d_out, int out_size, void* d_ws, size_t ws_size,
                              hipStream_t stream) {
    const float* outs = (const float*)d_in[0];
    const float* tgts = (const float*)d_in[1];
    float* out = (float*)d_out;                       // 1 float
    double* slots = (double*)d_ws;                    // 8 doubles
    unsigned int* counter = (unsigned int*)((char*)d_ws + NBLK * sizeof(double));

    mpse_hard8<<<dim3(NBLK), dim3(1024), 0, stream>>>(outs, tgts, slots, counter, out);
}